// Round 1
// baseline (406.461 us; speedup 1.0000x reference)
//
#include <hip/hip_runtime.h>
#include <math.h>

#define TOKENS 16384
#define DD 4096
#define NE 64
#define MBLK 256      // tokens per K1 block
#define KB 32         // k-chunk
#define XPITCH 33     // pad: transposed x reads conflict-free

// ---------------- K1: partial GEMM  logits_partial[s][t][e] ----------------
// grid: (TOKENS/MBLK) * S blocks, 256 threads (4 waves; wave w owns experts w*16..w*16+15)
__global__ __launch_bounds__(256, 2)
void k1_gemm(const float* __restrict__ x, const float* __restrict__ Wg,
             float* __restrict__ part, int S, int kPerSlice) {
  __shared__ float xs[MBLK * XPITCH];   // 33.8 KB
  __shared__ float wt[KB * NE];         // 8 KB, [kk][e]

  const int nm   = TOKENS / MBLK;       // 64
  const int mblk = blockIdx.x % nm;
  const int s    = blockIdx.x / nm;
  const int tid  = threadIdx.x;
  const int lane = tid & 63;
  const int wid  = tid >> 6;
  const int e0   = wid * 16;
  const long t0  = (long)mblk * MBLK;
  const int k0   = s * kPerSlice;
  const int nchunk = kPerSlice / KB;

  // staging assignments (coalesced global loads)
  const int xrow = tid >> 3;            // 0..31 (+32j)
  const int xcol = (tid & 7) << 2;      // 0..28 step 4
  const int wrow = tid >> 2;            // 0..63  (expert row of W)
  const int wcol = (tid & 3) << 3;      // 0,8,16,24

  const float* xbase = x + t0 * DD + k0;
  const float* wbase = Wg + (long)wrow * DD + k0 + wcol;

  float4 xr[8]; float4 wr0, wr1;
#pragma unroll
  for (int j = 0; j < 8; ++j)
    xr[j] = *(const float4*)(xbase + (long)(xrow + 32 * j) * DD + xcol);
  wr0 = *(const float4*)(wbase);
  wr1 = *(const float4*)(wbase + 4);

  float acc[4][16];
#pragma unroll
  for (int j = 0; j < 4; ++j)
#pragma unroll
    for (int q = 0; q < 16; ++q) acc[j][q] = 0.f;

  const int xb0 = lane * XPITCH;
  const int xb1 = (lane + 64) * XPITCH;
  const int xb2 = (lane + 128) * XPITCH;
  const int xb3 = (lane + 192) * XPITCH;

  for (int c = 0; c < nchunk; ++c) {
    // staged regs -> LDS
#pragma unroll
    for (int j = 0; j < 8; ++j) {
      float* p = &xs[(xrow + 32 * j) * XPITCH + xcol];
      p[0] = xr[j].x; p[1] = xr[j].y; p[2] = xr[j].z; p[3] = xr[j].w;
    }
    {
      const float* w0 = &wr0.x; const float* w1 = &wr1.x;
#pragma unroll
      for (int i = 0; i < 4; ++i) wt[(wcol + i) * NE + wrow] = w0[i];
#pragma unroll
      for (int i = 0; i < 4; ++i) wt[(wcol + 4 + i) * NE + wrow] = w1[i];
    }
    __syncthreads();
    // prefetch next chunk (latency hidden under FMAs)
    if (c + 1 < nchunk) {
      const float* xb = xbase + (c + 1) * KB;
#pragma unroll
      for (int j = 0; j < 8; ++j)
        xr[j] = *(const float4*)(xb + (long)(xrow + 32 * j) * DD + xcol);
      wr0 = *(const float4*)(wbase + (c + 1) * KB);
      wr1 = *(const float4*)(wbase + (c + 1) * KB + 4);
    }
    // compute: 4 tokens x 16 experts per lane
#pragma unroll 8
    for (int kk = 0; kk < KB; ++kk) {
      float xv0 = xs[xb0 + kk], xv1 = xs[xb1 + kk];
      float xv2 = xs[xb2 + kk], xv3 = xs[xb3 + kk];
      const float4* wv = (const float4*)&wt[kk * NE + e0];
#pragma unroll
      for (int q = 0; q < 4; ++q) {
        float4 wq = wv[q];
        acc[0][4*q+0] += xv0 * wq.x; acc[0][4*q+1] += xv0 * wq.y;
        acc[0][4*q+2] += xv0 * wq.z; acc[0][4*q+3] += xv0 * wq.w;
        acc[1][4*q+0] += xv1 * wq.x; acc[1][4*q+1] += xv1 * wq.y;
        acc[1][4*q+2] += xv1 * wq.z; acc[1][4*q+3] += xv1 * wq.w;
        acc[2][4*q+0] += xv2 * wq.x; acc[2][4*q+1] += xv2 * wq.y;
        acc[2][4*q+2] += xv2 * wq.z; acc[2][4*q+3] += xv2 * wq.w;
        acc[3][4*q+0] += xv3 * wq.x; acc[3][4*q+1] += xv3 * wq.y;
        acc[3][4*q+2] += xv3 * wq.z; acc[3][4*q+3] += xv3 * wq.w;
      }
    }
    __syncthreads();
  }

  float* pb = part + (long)s * TOKENS * NE + (t0 + lane) * NE + e0;
#pragma unroll
  for (int j = 0; j < 4; ++j) {
    float* pr = pb + (long)j * 64 * NE;
#pragma unroll
    for (int q = 0; q < 4; ++q)
      *(float4*)(pr + 4 * q) =
          make_float4(acc[j][4*q], acc[j][4*q+1], acc[j][4*q+2], acc[j][4*q+3]);
  }
}

// ------------- K2: reduce partials + softmax + top-2 + outputs -------------
// wave per token, lane = expert. grid: TOKENS/4 blocks x 256 threads.
__global__ __launch_bounds__(256)
void k2_finish(const float* __restrict__ part, int S, float* __restrict__ out) {
  const int tid  = threadIdx.x;
  const int lane = tid & 63;
  const int wv   = tid >> 6;
  const long t   = (long)blockIdx.x * 4 + wv;

  const float* p = part + t * NE + lane;
  float logit = 0.f;
  for (int s = 0; s < S; ++s) logit += p[(long)s * TOKENS * NE];

  // logits out (region starts at 4*TOKENS floats)
  out[4 * TOKENS + t * NE + lane] = logit;

  // argmax (tie -> lowest index, matches jax.lax.top_k)
  float v = logit; int i = lane;
#pragma unroll
  for (int off = 32; off; off >>= 1) {
    float ov = __shfl_xor(v, off);
    int   oi = __shfl_xor(i, off);
    if (ov > v || (ov == v && oi < i)) { v = ov; i = oi; }
  }
  const float m = v; const int i1 = i;

  float v2 = (lane == i1) ? -INFINITY : logit;
  float vv = v2; int ii = lane;
#pragma unroll
  for (int off = 32; off; off >>= 1) {
    float ov = __shfl_xor(vv, off);
    int   oi = __shfl_xor(ii, off);
    if (ov > vv || (ov == vv && oi < ii)) { vv = ov; ii = oi; }
  }
  const int i2 = ii;

  // full softmax denominator over all 64 experts
  float z = expf(logit - m);
  float Z = z;
#pragma unroll
  for (int off = 32; off; off >>= 1) Z += __shfl_xor(Z, off);

  float p1 = __shfl(z, i1) / Z;
  float p2 = __shfl(z, i2) / Z;

  if (lane == 0) {
    float denom = p1 + p2 + 1e-9f;
    out[t * 2 + 0] = (float)i1;               // indices region [0, 2*TOKENS)
    out[t * 2 + 1] = (float)i2;
    out[2 * TOKENS + t * 2 + 0] = p1 / denom; // weights region [2T, 4T)
    out[2 * TOKENS + t * 2 + 1] = p2 / denom;
  }
}

extern "C" void kernel_launch(void* const* d_in, const int* in_sizes, int n_in,
                              void* d_out, int out_size, void* d_ws, size_t ws_size,
                              hipStream_t stream) {
  const float* x  = (const float*)d_in[0];
  const float* Wg = (const float*)d_in[1];
  float* out = (float*)d_out;

  const size_t sliceBytes = (size_t)TOKENS * NE * sizeof(float); // 4.19 MB
  int S = 8;
  while (S > 1 && (size_t)S * sliceBytes > ws_size) S >>= 1;
  float* part;
  if ((size_t)S * sliceBytes <= ws_size) {
    part = (float*)d_ws;
  } else {               // tiny ws fallback: S=1 partials ARE the logits
    S = 1;
    part = out + 4 * TOKENS;
  }
  const int kPerSlice = DD / S;

  k1_gemm<<<dim3((TOKENS / MBLK) * S), 256, 0, stream>>>(x, Wg, part, S, kPerSlice);
  k2_finish<<<dim3(TOKENS / 4), 256, 0, stream>>>(part, S, out);
}